// Round 6
// baseline (797.210 us; speedup 1.0000x reference)
//
#include <hip/hip_runtime.h>

// Problem constants
#define NN 50000
#define EE 1600000
#define FF 128
#define HH 64
#define CC 40
#define NB 196                 // ceil(NN/256) scan blocks
#define SLICE2 25000           // NN/2 node-slice for 2-slice kernels

// deg-hist: 64 chunks x 2 slices; cnt-hist & fill: 16 coarse chunks x 2 slices
#define NCHUNK_D 64
#define CHUNKE_D (EE / NCHUNK_D)   // 25000
#define NCHUNK_C 16
#define CHUNKE_C (EE / NCHUNK_C)   // 100000

// ---------- bf16 helpers (storage-only; math in fp32) ----------
static __device__ __forceinline__ float bf2f(unsigned short u) {
    union { unsigned int i; float f; } c; c.i = ((unsigned int)u) << 16; return c.f;
}
static __device__ __forceinline__ unsigned short f2bf(float x) {  // RNE
    union { float f; unsigned int i; } c; c.f = x;
    unsigned int r = c.i + 0x7FFFu + ((c.i >> 16) & 1u);
    return (unsigned short)(r >> 16);
}

// ---------- deg histogram: pdeg[c][n] = sum of w over src in chunk c ----------
__global__ __launch_bounds__(1024) void deg_hist_kernel(
    const int* __restrict__ src, const float* __restrict__ w,
    float* __restrict__ pdeg) {
    __shared__ float ldeg[SLICE2];    // 100 KB
    int s = blockIdx.x & 1;
    int c = blockIdx.x >> 1;
    int base = s * SLICE2;
    for (int i = threadIdx.x; i < SLICE2; i += 1024) ldeg[i] = 0.f;
    __syncthreads();
    int e0 = c * CHUNKE_D;
    for (int e = e0 + threadIdx.x; e < e0 + CHUNKE_D; e += 1024) {
        int se = src[e];
        unsigned us = (unsigned)(se - base);
        if (us < SLICE2) atomicAdd(&ldeg[us], w[e]);
    }
    __syncthreads();
    for (int i = threadIdx.x; i < SLICE2; i += 1024)
        pdeg[(size_t)c * NN + base + i] = ldeg[i];
}

// ---------- cnt histogram: pcnt[c][n] = #edges with dst n in coarse chunk c ----------
__global__ __launch_bounds__(1024) void cnt_hist_kernel(
    const int* __restrict__ dst, int* __restrict__ pcnt) {
    __shared__ int lcnt[SLICE2];      // 100 KB
    int s = blockIdx.x & 1;
    int c = blockIdx.x >> 1;
    int base = s * SLICE2;
    for (int i = threadIdx.x; i < SLICE2; i += 1024) lcnt[i] = 0;
    __syncthreads();
    int e0 = c * CHUNKE_C;
    for (int e = e0 + threadIdx.x; e < e0 + CHUNKE_C; e += 1024) {
        int de = dst[e];
        unsigned ud = (unsigned)(de - base);
        if (ud < SLICE2) atomicAdd(&lcnt[ud], 1);
    }
    __syncthreads();
    for (int i = threadIdx.x; i < SLICE2; i += 1024)
        pcnt[(size_t)c * NN + base + i] = lcnt[i];
}

// ---------- per-node reduce: deg sum, pcnt -> chunk-exclusive offsets ----------
__global__ void reduce_kernel(const float* __restrict__ pdeg, int* __restrict__ pcnt,
                              int* __restrict__ cnt, float* __restrict__ dis,
                              float* __restrict__ diag) {
    int n = blockIdx.x * blockDim.x + threadIdx.x;
    if (n >= NN) return;
    float dsum = 0.f;
    for (int c = 0; c < NCHUNK_D; ++c) dsum += pdeg[(size_t)c * NN + n];
    int run = 0;
    for (int c = 0; c < NCHUNK_C; ++c) {
        int t = pcnt[(size_t)c * NN + n];
        pcnt[(size_t)c * NN + n] = run;
        run += t;
    }
    cnt[n] = run;
    dis[n]  = (dsum > 0.f) ? rsqrtf(fmaxf(dsum, 1e-12f)) : 0.f;
    diag[n] = (dsum > 0.f) ? 0.f : -1.f;
}

// ---------- 3-kernel exclusive scan cnt -> row_start ----------
__global__ void scanA_kernel(const int* __restrict__ cnt, int* __restrict__ bsum) {
    __shared__ int sh[256];
    int i = blockIdx.x * 256 + threadIdx.x;
    sh[threadIdx.x] = (i < NN) ? cnt[i] : 0;
    __syncthreads();
    for (int off = 128; off > 0; off >>= 1) {
        if (threadIdx.x < off) sh[threadIdx.x] += sh[threadIdx.x + off];
        __syncthreads();
    }
    if (threadIdx.x == 0) bsum[blockIdx.x] = sh[0];
}

__global__ void scanB_kernel(const int* __restrict__ bsum, int* __restrict__ boff,
                             int* __restrict__ row_start) {
    if (threadIdx.x == 0) {
        int run = 0;
        for (int b = 0; b < NB; ++b) { boff[b] = run; run += bsum[b]; }
        row_start[NN] = run;
    }
}

__global__ void scanC_kernel(const int* __restrict__ cnt, const int* __restrict__ boff,
                             int* __restrict__ row_start) {
    __shared__ int sh[256];
    int t = threadIdx.x;
    int i = blockIdx.x * 256 + t;
    int v = (i < NN) ? cnt[i] : 0;
    sh[t] = v;
    __syncthreads();
    for (int off = 1; off < 256; off <<= 1) {
        int x = (t >= off) ? sh[t - off] : 0;
        __syncthreads();
        sh[t] += x;
        __syncthreads();
    }
    if (i < NN) row_start[i] = boff[blockIdx.x] + sh[t] - v;
}

// ---------- CSR fill, int2-packed entries, LDS cursors ----------
__global__ __launch_bounds__(1024) void fill_kernel(
    const int* __restrict__ src, const int* __restrict__ dst,
    const float* __restrict__ w, const float* __restrict__ dis,
    const int* __restrict__ row_start, const int* __restrict__ pcnt,
    int2* __restrict__ csr) {
    __shared__ int lcur[SLICE2];      // 100 KB
    int s = blockIdx.x & 1;
    int c = blockIdx.x >> 1;
    int base = s * SLICE2;
    for (int i = threadIdx.x; i < SLICE2; i += 1024) lcur[i] = 0;
    __syncthreads();
    int e0 = c * CHUNKE_C;
    for (int e = e0 + threadIdx.x; e < e0 + CHUNKE_C; e += 1024) {
        int de = dst[e];
        unsigned ud = (unsigned)(de - base);
        if (ud < SLICE2) {
            int se = src[e];
            int off = atomicAdd(&lcur[ud], 1);
            int pos = row_start[de] + pcnt[(size_t)c * NN + de] + off;
            float wn = -dis[se] * w[e] * dis[de];
            csr[pos] = make_int2(se, __float_as_int(wn));
        }
    }
}

// ---------- generalized propagation ----------
// out[n,f] = alphaL*(diag[n]*a[n,f] + sum_in w*a[src,f]) + beta1*p1[n,f]
//            + beta2*p2[n,f] (+bias) (+relu)
// a: bf16, gathered (the only random-access array). p1/p2: fp32, coalesced.
// OUT_T: ushort (bf16) or float. One wave per node, lane = feature.
template <int FACT, typename OUT_T>
__global__ __launch_bounds__(256) void prop2_kernel(
    const unsigned short* __restrict__ a, int aStride, float alphaL,
    const float* __restrict__ p1, float beta1,
    const float* __restrict__ p2, float beta2, int pStride,
    const float* __restrict__ bias, int doRelu, int FOUT, int outStride,
    const float* __restrict__ diag, const int* __restrict__ rs,
    const int2* __restrict__ csr, OUT_T* __restrict__ out) {
    int lane = threadIdx.x & 63;
    int wave = threadIdx.x >> 6;
    int n = blockIdx.x * 4 + wave;   // NN divisible by 4
    int f = lane;
    float acc = 0.f;
    if (f < FACT) {
        acc = diag[n] * bf2f(a[(size_t)n * aStride + f]);
        int j0 = rs[n], j1 = rs[n + 1];
        int j = j0;
        for (; j + 8 <= j1; j += 8) {
            int   s[8];
            float w[8];
            #pragma unroll
            for (int u = 0; u < 8; ++u) {
                int2 cw = csr[j + u];
                s[u] = cw.x;
                w[u] = __int_as_float(cw.y);
            }
            float v[8];
            #pragma unroll
            for (int u = 0; u < 8; ++u) v[u] = bf2f(a[(size_t)s[u] * aStride + f]);
            #pragma unroll
            for (int u = 0; u < 8; ++u) acc = fmaf(w[u], v[u], acc);
        }
        for (; j < j1; ++j) {
            int2 cw = csr[j];
            acc = fmaf(__int_as_float(cw.y),
                       bf2f(a[(size_t)cw.x * aStride + f]), acc);
        }
    }
    if (f < FOUT) {
        float r = alphaL * acc + beta1 * p1[(size_t)n * pStride + f];
        if (beta2 != 0.f) r = fmaf(beta2, p2[(size_t)n * pStride + f], r);
        if (bias) r += bias[f];
        if (doRelu) r = fmaxf(r, 0.f);
        OUT_T o;
        if constexpr (sizeof(OUT_T) == 2) o = f2bf(r); else o = r;
        out[(size_t)n * outStride + f] = o;
    }
}

// ---------- GEMM1: Yf[n, ct*64+j] = sum_f x[n,f]*W1[(ct*128+f)*64+j]; ct=3 also bf16 ----------
__global__ __launch_bounds__(256) void gemm1_kernel(
    const float* __restrict__ x, const float* __restrict__ W,
    float* __restrict__ Yf, unsigned short* __restrict__ y3b) {
    __shared__ float As[64][36];
    __shared__ float Bs[32][64];
    int t = threadIdx.x;
    int m0 = blockIdx.x * 64;
    int ct = blockIdx.y;
    int tr = t / 16, tc = t % 16;
    int kq = t % 8,  ms = t / 8;
    int jb = t % 16, fb = t / 16;
    float acc[4][4] = {};
    for (int kb = 0; kb < 4; ++kb) {
        __syncthreads();
        #pragma unroll
        for (int p = 0; p < 2; ++p) {
            int m = ms + 32 * p;
            int row = m0 + m;
            float4 vv = make_float4(0.f, 0.f, 0.f, 0.f);
            if (row < NN) vv = *(const float4*)(x + (size_t)row * FF + kb * 32 + kq * 4);
            *(float4*)&As[m][kq * 4] = vv;
        }
        const float* Wb = W + ((size_t)ct * 128 + kb * 32) * HH;
        #pragma unroll
        for (int p = 0; p < 2; ++p) {
            int fi = fb + 16 * p;
            float4 vv = *(const float4*)(Wb + fi * HH + jb * 4);
            *(float4*)&Bs[fi][jb * 4] = vv;
        }
        __syncthreads();
        #pragma unroll 8
        for (int k = 0; k < 32; ++k) {
            float a0 = As[tr * 4 + 0][k], a1 = As[tr * 4 + 1][k];
            float a2 = As[tr * 4 + 2][k], a3 = As[tr * 4 + 3][k];
            float4 b = *(float4*)&Bs[k][tc * 4];
            acc[0][0] = fmaf(a0, b.x, acc[0][0]); acc[0][1] = fmaf(a0, b.y, acc[0][1]);
            acc[0][2] = fmaf(a0, b.z, acc[0][2]); acc[0][3] = fmaf(a0, b.w, acc[0][3]);
            acc[1][0] = fmaf(a1, b.x, acc[1][0]); acc[1][1] = fmaf(a1, b.y, acc[1][1]);
            acc[1][2] = fmaf(a1, b.z, acc[1][2]); acc[1][3] = fmaf(a1, b.w, acc[1][3]);
            acc[2][0] = fmaf(a2, b.x, acc[2][0]); acc[2][1] = fmaf(a2, b.y, acc[2][1]);
            acc[2][2] = fmaf(a2, b.z, acc[2][2]); acc[2][3] = fmaf(a2, b.w, acc[2][3]);
            acc[3][0] = fmaf(a3, b.x, acc[3][0]); acc[3][1] = fmaf(a3, b.y, acc[3][1]);
            acc[3][2] = fmaf(a3, b.z, acc[3][2]); acc[3][3] = fmaf(a3, b.w, acc[3][3]);
        }
    }
    #pragma unroll
    for (int r = 0; r < 4; ++r) {
        int n = m0 + tr * 4 + r;
        if (n < NN) {
            *(float4*)(Yf + (size_t)n * 256 + ct * 64 + tc * 4) =
                make_float4(acc[r][0], acc[r][1], acc[r][2], acc[r][3]);
            if (ct == 3) {
                ushort4 u4;
                u4.x = f2bf(acc[r][0]); u4.y = f2bf(acc[r][1]);
                u4.z = f2bf(acc[r][2]); u4.w = f2bf(acc[r][3]);
                *(ushort4*)(y3b + (size_t)n * 64 + tc * 4) = u4;
            }
        }
    }
}

// ---------- GEMM2: Y2f[n, kt*64+j] = sum_f h[n,f]*W2[(kt*64+f)*40+j]; kt=3 also bf16 ----------
__global__ __launch_bounds__(256) void gemm2_kernel(
    const float* __restrict__ h, const float* __restrict__ W,
    float* __restrict__ Y2f, unsigned short* __restrict__ y3b2) {
    __shared__ float As[128][36];
    __shared__ float Bs[32][40];
    int t = threadIdx.x;
    int m0 = blockIdx.x * 128;
    int kt = blockIdx.y;
    int tr = t / 8, tc = t % 8;
    int kq = t % 8, ms = t / 8;
    float acc[4][5] = {};
    for (int kb = 0; kb < 2; ++kb) {
        __syncthreads();
        #pragma unroll
        for (int p = 0; p < 4; ++p) {
            int m = ms + 32 * p;
            int row = m0 + m;
            float4 vv = make_float4(0.f, 0.f, 0.f, 0.f);
            if (row < NN) vv = *(const float4*)(h + (size_t)row * HH + kb * 32 + kq * 4);
            *(float4*)&As[m][kq * 4] = vv;
        }
        const float* Wb = W + ((size_t)kt * 64 + kb * 32) * CC;
        for (int i = t; i < 32 * CC; i += 256) ((float*)Bs)[i] = Wb[i];
        __syncthreads();
        #pragma unroll 4
        for (int k = 0; k < 32; ++k) {
            float a0 = As[tr * 4 + 0][k], a1 = As[tr * 4 + 1][k];
            float a2 = As[tr * 4 + 2][k], a3 = As[tr * 4 + 3][k];
            #pragma unroll
            for (int c = 0; c < 5; ++c) {
                float b = Bs[k][tc * 5 + c];
                acc[0][c] = fmaf(a0, b, acc[0][c]);
                acc[1][c] = fmaf(a1, b, acc[1][c]);
                acc[2][c] = fmaf(a2, b, acc[2][c]);
                acc[3][c] = fmaf(a3, b, acc[3][c]);
            }
        }
    }
    #pragma unroll
    for (int r = 0; r < 4; ++r) {
        int n = m0 + tr * 4 + r;
        if (n < NN) {
            float* orow = Y2f + (size_t)n * 256 + kt * 64;
            #pragma unroll
            for (int c = 0; c < 5; ++c) orow[tc * 5 + c] = acc[r][c];
            if (tc < 6) {  // zero pad cols 40..63 of this slab
                #pragma unroll
                for (int c = 0; c < 4; ++c) orow[40 + tc * 4 + c] = 0.f;
            }
            if (kt == 3) {
                unsigned short* brow = y3b2 + (size_t)n * 64;
                #pragma unroll
                for (int c = 0; c < 5; ++c) brow[tc * 5 + c] = f2bf(acc[r][c]);
                if (tc < 6) {
                    #pragma unroll
                    for (int c = 0; c < 4; ++c) brow[40 + tc * 4 + c] = 0;
                }
            }
        }
    }
}

// ---------- launcher ----------
extern "C" void kernel_launch(void* const* d_in, const int* in_sizes, int n_in,
                              void* d_out, int out_size, void* d_ws, size_t ws_size,
                              hipStream_t stream) {
    const float* x    = (const float*)d_in[0];
    const int*   eidx = (const int*)d_in[1];
    const float* ew   = (const float*)d_in[2];
    const float* W1   = (const float*)d_in[3];
    const float* b1   = (const float*)d_in[4];
    const float* W2   = (const float*)d_in[5];
    const float* b2   = (const float*)d_in[6];
    float* out = (float*)d_out;

    const int* src = eidx;
    const int* dst = eidx + EE;

    // workspace carve-up
    float* p = (float*)d_ws;
    int2* csr = (int2*)p;             p += (size_t)2 * EE;        // 12.8 MB
    float* dis  = p;                  p += ((NN + 63) / 64) * 64;
    float* diag = p;                  p += ((NN + 63) / 64) * 64;
    float* Yf   = p;                  p += (size_t)NN * 256;      // 51.2 MB (layer-1/2 slabs)
    unsigned short* y3b = (unsigned short*)p;  p += (size_t)NN * 32;  // bf16 [N,64]
    unsigned short* u   = (unsigned short*)p;  p += (size_t)NN * 32;
    unsigned short* v   = (unsigned short*)p;  p += (size_t)NN * 32;
    float* h    = p;                  p += (size_t)NN * 64;       // 12.8 MB
    int* cnt       = (int*)p;
    int* row_start = cnt + NN;            // NN+1
    int* bsum      = row_start + NN + 1;
    int* boff      = bsum + NB;

    // aliases (stream-ordered disjoint lifetimes)
    float* pdeg = Yf;                                  // 64*NN floats
    int*   pcnt = (int*)(Yf + (size_t)NCHUNK_D * NN);  // 16*NN ints
    float* Y2f = Yf;
    unsigned short* y3b2 = y3b;
    unsigned short* u2 = u;
    unsigned short* v2 = v;

    const int B = 256;
    deg_hist_kernel<<<NCHUNK_D * 2, 1024, 0, stream>>>(src, ew, pdeg);
    cnt_hist_kernel<<<NCHUNK_C * 2, 1024, 0, stream>>>(dst, pcnt);
    reduce_kernel<<<(NN + B - 1) / B, B, 0, stream>>>(pdeg, pcnt, cnt, dis, diag);
    scanA_kernel<<<NB, 256, 0, stream>>>(cnt, bsum);
    scanB_kernel<<<1, 64, 0, stream>>>(bsum, boff, row_start);
    scanC_kernel<<<NB, 256, 0, stream>>>(cnt, boff, row_start);
    fill_kernel<<<NCHUNK_C * 2, 1024, 0, stream>>>(src, dst, ew, dis, row_start, pcnt, csr);

    int pgrid = NN / 4;

    // ---- layer 1: project first, then 3 props in 64-dim ----
    gemm1_kernel<<<dim3((NN + 63) / 64, 4), 256, 0, stream>>>(x, W1, Yf, y3b);
    // u = 4*Lhat(y3) + 2*y2
    prop2_kernel<64, unsigned short><<<pgrid, 256, 0, stream>>>(
        y3b, 64, 4.f, Yf + 128, 2.f, nullptr, 0.f, 256,
        nullptr, 0, 64, 64, diag, row_start, csr, u);
    // v = Lhat(u) + y1 - 3*y3
    prop2_kernel<64, unsigned short><<<pgrid, 256, 0, stream>>>(
        u, 64, 1.f, Yf + 64, 1.f, Yf + 192, -3.f, 256,
        nullptr, 0, 64, 64, diag, row_start, csr, v);
    // h = relu(Lhat(v) + y0 - y2 + b1)   (fp32 out)
    prop2_kernel<64, float><<<pgrid, 256, 0, stream>>>(
        v, 64, 1.f, Yf, 1.f, Yf + 128, -1.f, 256,
        b1, 1, 64, 64, diag, row_start, csr, h);

    // ---- layer 2: project, then 3 props in 40(48)-dim ----
    gemm2_kernel<<<dim3((NN + 127) / 128, 4), 256, 0, stream>>>(h, W2, Y2f, y3b2);
    // u2 = 4*Lhat(y'3) + 2*y'2
    prop2_kernel<48, unsigned short><<<pgrid, 256, 0, stream>>>(
        y3b2, 64, 4.f, Y2f + 128, 2.f, nullptr, 0.f, 256,
        nullptr, 0, 48, 64, diag, row_start, csr, u2);
    // v2 = Lhat(u2) + y'1 - 3*y'3
    prop2_kernel<48, unsigned short><<<pgrid, 256, 0, stream>>>(
        u2, 64, 1.f, Y2f + 64, 1.f, Y2f + 192, -3.f, 256,
        nullptr, 0, 48, 64, diag, row_start, csr, v2);
    // out = Lhat(v2) + y'0 - y'2 + b2   (fp32 out, stride 40)
    prop2_kernel<48, float><<<pgrid, 256, 0, stream>>>(
        v2, 64, 1.f, Y2f, 1.f, Y2f + 128, -1.f, 256,
        b2, 0, 40, 40, diag, row_start, csr, out);
}

// Round 7
// 596.709 us; speedup vs baseline: 1.3360x; 1.3360x over previous
//
#include <hip/hip_runtime.h>

// Problem constants
#define NN 50000
#define EE 1600000
#define FF 128
#define HH 64
#define CC 40
#define NB 196                 // ceil(NN/256) scan blocks

// merged hist: 64 edge-chunks x 4 node-slices = 256 blocks
#define NCH 64
#define CHE (EE / NCH)         // 25000
#define NSL 4
#define SLN (NN / NSL)         // 12500
// fill: 16 coarse edge-chunks x 16 node-slices = 256 blocks
#define NCHF 16
#define CHEF (EE / NCHF)       // 100000
#define NSLF 16
#define SLNF (NN / NSLF)       // 3125

// ---------- bf16 helpers (storage-only; math in fp32) ----------
static __device__ __forceinline__ float bf2f(unsigned short u) {
    union { unsigned int i; float f; } c; c.i = ((unsigned int)u) << 16; return c.f;
}
static __device__ __forceinline__ unsigned short f2bf(float x) {  // RNE
    union { float f; unsigned int i; } c; c.f = x;
    unsigned int r = c.i + 0x7FFFu + ((c.i >> 16) & 1u);
    return (unsigned short)(r >> 16);
}

// ---------- merged histogram: pdeg[c][n] = sum w over src; pcnt64[c][n] = #dst ----------
// 16-bit packed LDS counters (2 nodes per uint; max in-degree << 65536).
__global__ __launch_bounds__(1024) void hist_kernel(
    const int* __restrict__ src, const int* __restrict__ dst,
    const float* __restrict__ w,
    float* __restrict__ pdeg, unsigned short* __restrict__ pcnt64) {
    __shared__ float        ldeg[SLN];        // 50 KB
    __shared__ unsigned int lcnt[SLN / 2];    // 25 KB, two 16-bit fields per word
    int s = blockIdx.x % NSL;
    int c = blockIdx.x / NSL;
    int base = s * SLN;
    for (int i = threadIdx.x; i < SLN; i += 1024) ldeg[i] = 0.f;
    for (int i = threadIdx.x; i < SLN / 2; i += 1024) lcnt[i] = 0u;
    __syncthreads();
    int e0 = c * CHE;
    for (int e = e0 + threadIdx.x; e < e0 + CHE; e += 1024) {
        int se = src[e], de = dst[e];
        unsigned us = (unsigned)(se - base), ud = (unsigned)(de - base);
        if (us < SLN) atomicAdd(&ldeg[us], w[e]);
        if (ud < SLN) atomicAdd(&lcnt[ud >> 1], 1u << (16 * (ud & 1)));
    }
    __syncthreads();
    for (int i = threadIdx.x; i < SLN; i += 1024) {
        pdeg[(size_t)c * NN + base + i] = ldeg[i];
        pcnt64[(size_t)c * NN + base + i] =
            (unsigned short)((lcnt[i >> 1] >> (16 * (i & 1))) & 0xFFFFu);
    }
}

// ---------- per-node reduce; fold 64-chunk counts into 16-coarse-chunk offsets ----------
__global__ void reduce_kernel(const float* __restrict__ pdeg,
                              const unsigned short* __restrict__ pcnt64,
                              int* __restrict__ pcnt16, int* __restrict__ cnt,
                              float* __restrict__ dis, float* __restrict__ diag) {
    int n = blockIdx.x * blockDim.x + threadIdx.x;
    if (n >= NN) return;
    float dsum = 0.f;
    for (int c = 0; c < NCH; ++c) dsum += pdeg[(size_t)c * NN + n];
    int run = 0;
    for (int c16 = 0; c16 < NCHF; ++c16) {
        pcnt16[(size_t)c16 * NN + n] = run;   // coarse-chunk-exclusive offset
        #pragma unroll
        for (int q = 0; q < 4; ++q)
            run += pcnt64[(size_t)(c16 * 4 + q) * NN + n];
    }
    cnt[n] = run;
    dis[n]  = (dsum > 0.f) ? rsqrtf(fmaxf(dsum, 1e-12f)) : 0.f;
    diag[n] = (dsum > 0.f) ? 0.f : -1.f;
}

// ---------- 3-kernel exclusive scan cnt -> row_start ----------
__global__ void scanA_kernel(const int* __restrict__ cnt, int* __restrict__ bsum) {
    __shared__ int sh[256];
    int i = blockIdx.x * 256 + threadIdx.x;
    sh[threadIdx.x] = (i < NN) ? cnt[i] : 0;
    __syncthreads();
    for (int off = 128; off > 0; off >>= 1) {
        if (threadIdx.x < off) sh[threadIdx.x] += sh[threadIdx.x + off];
        __syncthreads();
    }
    if (threadIdx.x == 0) bsum[blockIdx.x] = sh[0];
}

__global__ void scanB_kernel(const int* __restrict__ bsum, int* __restrict__ boff,
                             int* __restrict__ row_start) {
    if (threadIdx.x == 0) {
        int run = 0;
        for (int b = 0; b < NB; ++b) { boff[b] = run; run += bsum[b]; }
        row_start[NN] = run;
    }
}

__global__ void scanC_kernel(const int* __restrict__ cnt, const int* __restrict__ boff,
                             int* __restrict__ row_start) {
    __shared__ int sh[256];
    int t = threadIdx.x;
    int i = blockIdx.x * 256 + t;
    int v = (i < NN) ? cnt[i] : 0;
    sh[t] = v;
    __syncthreads();
    for (int off = 1; off < 256; off <<= 1) {
        int x = (t >= off) ? sh[t - off] : 0;
        __syncthreads();
        sh[t] += x;
        __syncthreads();
    }
    if (i < NN) row_start[i] = boff[blockIdx.x] + sh[t] - v;
}

// ---------- CSR fill: 16 coarse chunks x 16 slices, packed 16-bit LDS cursors ----------
__global__ __launch_bounds__(1024) void fill_kernel(
    const int* __restrict__ src, const int* __restrict__ dst,
    const float* __restrict__ w, const float* __restrict__ dis,
    const int* __restrict__ row_start, const int* __restrict__ pcnt16,
    int2* __restrict__ csr) {
    __shared__ unsigned int lcur[(SLNF + 1) / 2];   // 6.3 KB
    int s = blockIdx.x % NSLF;
    int c = blockIdx.x / NSLF;
    int base = s * SLNF;
    for (int i = threadIdx.x; i < (SLNF + 1) / 2; i += 1024) lcur[i] = 0u;
    __syncthreads();
    int e0 = c * CHEF;
    for (int e = e0 + threadIdx.x; e < e0 + CHEF; e += 1024) {
        int de = dst[e];
        unsigned ud = (unsigned)(de - base);
        if (ud < SLNF) {
            int se = src[e];
            unsigned sh = 16 * (ud & 1);
            unsigned old = atomicAdd(&lcur[ud >> 1], 1u << sh);
            int off = (int)((old >> sh) & 0xFFFFu);
            int pos = row_start[de] + pcnt16[(size_t)c * NN + de] + off;
            float wn = -dis[se] * w[e] * dis[de];
            csr[pos] = make_int2(se, __float_as_int(wn));
        }
    }
}

// ---------- generalized propagation (bf16 gathered operand, int2 CSR) ----------
template <int FACT, typename OUT_T>
__global__ __launch_bounds__(256) void prop2_kernel(
    const unsigned short* __restrict__ a, int aStride, float alphaL,
    const float* __restrict__ p1, float beta1,
    const float* __restrict__ p2, float beta2, int pStride,
    const float* __restrict__ bias, int doRelu, int FOUT, int outStride,
    const float* __restrict__ diag, const int* __restrict__ rs,
    const int2* __restrict__ csr, OUT_T* __restrict__ out) {
    int lane = threadIdx.x & 63;
    int wave = threadIdx.x >> 6;
    int n = blockIdx.x * 4 + wave;   // NN divisible by 4
    int f = lane;
    float acc = 0.f;
    if (f < FACT) {
        acc = diag[n] * bf2f(a[(size_t)n * aStride + f]);
        int j0 = rs[n], j1 = rs[n + 1];
        int j = j0;
        for (; j + 8 <= j1; j += 8) {
            int   s[8];
            float w[8];
            #pragma unroll
            for (int u = 0; u < 8; ++u) {
                int2 cw = csr[j + u];
                s[u] = cw.x;
                w[u] = __int_as_float(cw.y);
            }
            float v[8];
            #pragma unroll
            for (int u = 0; u < 8; ++u) v[u] = bf2f(a[(size_t)s[u] * aStride + f]);
            #pragma unroll
            for (int u = 0; u < 8; ++u) acc = fmaf(w[u], v[u], acc);
        }
        for (; j < j1; ++j) {
            int2 cw = csr[j];
            acc = fmaf(__int_as_float(cw.y),
                       bf2f(a[(size_t)cw.x * aStride + f]), acc);
        }
    }
    if (f < FOUT) {
        float r = alphaL * acc + beta1 * p1[(size_t)n * pStride + f];
        if (beta2 != 0.f) r = fmaf(beta2, p2[(size_t)n * pStride + f], r);
        if (bias) r += bias[f];
        if (doRelu) r = fmaxf(r, 0.f);
        OUT_T o;
        if constexpr (sizeof(OUT_T) == 2) o = f2bf(r); else o = r;
        out[(size_t)n * outStride + f] = o;
    }
}

// ---------- GEMM1: Yf[n, ct*64+j] = sum_f x[n,f]*W1[(ct*128+f)*64+j]; ct=3 also bf16 ----------
__global__ __launch_bounds__(256) void gemm1_kernel(
    const float* __restrict__ x, const float* __restrict__ W,
    float* __restrict__ Yf, unsigned short* __restrict__ y3b) {
    __shared__ float As[64][36];
    __shared__ float Bs[32][64];
    int t = threadIdx.x;
    int m0 = blockIdx.x * 64;
    int ct = blockIdx.y;
    int tr = t / 16, tc = t % 16;
    int kq = t % 8,  ms = t / 8;
    int jb = t % 16, fb = t / 16;
    float acc[4][4] = {};
    for (int kb = 0; kb < 4; ++kb) {
        __syncthreads();
        #pragma unroll
        for (int p = 0; p < 2; ++p) {
            int m = ms + 32 * p;
            int row = m0 + m;
            float4 vv = make_float4(0.f, 0.f, 0.f, 0.f);
            if (row < NN) vv = *(const float4*)(x + (size_t)row * FF + kb * 32 + kq * 4);
            *(float4*)&As[m][kq * 4] = vv;
        }
        const float* Wb = W + ((size_t)ct * 128 + kb * 32) * HH;
        #pragma unroll
        for (int p = 0; p < 2; ++p) {
            int fi = fb + 16 * p;
            float4 vv = *(const float4*)(Wb + fi * HH + jb * 4);
            *(float4*)&Bs[fi][jb * 4] = vv;
        }
        __syncthreads();
        #pragma unroll 8
        for (int k = 0; k < 32; ++k) {
            float a0 = As[tr * 4 + 0][k], a1 = As[tr * 4 + 1][k];
            float a2 = As[tr * 4 + 2][k], a3 = As[tr * 4 + 3][k];
            float4 b = *(float4*)&Bs[k][tc * 4];
            acc[0][0] = fmaf(a0, b.x, acc[0][0]); acc[0][1] = fmaf(a0, b.y, acc[0][1]);
            acc[0][2] = fmaf(a0, b.z, acc[0][2]); acc[0][3] = fmaf(a0, b.w, acc[0][3]);
            acc[1][0] = fmaf(a1, b.x, acc[1][0]); acc[1][1] = fmaf(a1, b.y, acc[1][1]);
            acc[1][2] = fmaf(a1, b.z, acc[1][2]); acc[1][3] = fmaf(a1, b.w, acc[1][3]);
            acc[2][0] = fmaf(a2, b.x, acc[2][0]); acc[2][1] = fmaf(a2, b.y, acc[2][1]);
            acc[2][2] = fmaf(a2, b.z, acc[2][2]); acc[2][3] = fmaf(a2, b.w, acc[2][3]);
            acc[3][0] = fmaf(a3, b.x, acc[3][0]); acc[3][1] = fmaf(a3, b.y, acc[3][1]);
            acc[3][2] = fmaf(a3, b.z, acc[3][2]); acc[3][3] = fmaf(a3, b.w, acc[3][3]);
        }
    }
    #pragma unroll
    for (int r = 0; r < 4; ++r) {
        int n = m0 + tr * 4 + r;
        if (n < NN) {
            *(float4*)(Yf + (size_t)n * 256 + ct * 64 + tc * 4) =
                make_float4(acc[r][0], acc[r][1], acc[r][2], acc[r][3]);
            if (ct == 3) {
                ushort4 u4;
                u4.x = f2bf(acc[r][0]); u4.y = f2bf(acc[r][1]);
                u4.z = f2bf(acc[r][2]); u4.w = f2bf(acc[r][3]);
                *(ushort4*)(y3b + (size_t)n * 64 + tc * 4) = u4;
            }
        }
    }
}

// ---------- GEMM2: Y2f[n, kt*64+j] = sum_f h[n,f]*W2[(kt*64+f)*40+j]; kt=3 also bf16 ----------
__global__ __launch_bounds__(256) void gemm2_kernel(
    const float* __restrict__ h, const float* __restrict__ W,
    float* __restrict__ Y2f, unsigned short* __restrict__ y3b2) {
    __shared__ float As[128][36];
    __shared__ float Bs[32][40];
    int t = threadIdx.x;
    int m0 = blockIdx.x * 128;
    int kt = blockIdx.y;
    int tr = t / 8, tc = t % 8;
    int kq = t % 8, ms = t / 8;
    float acc[4][5] = {};
    for (int kb = 0; kb < 2; ++kb) {
        __syncthreads();
        #pragma unroll
        for (int p = 0; p < 4; ++p) {
            int m = ms + 32 * p;
            int row = m0 + m;
            float4 vv = make_float4(0.f, 0.f, 0.f, 0.f);
            if (row < NN) vv = *(const float4*)(h + (size_t)row * HH + kb * 32 + kq * 4);
            *(float4*)&As[m][kq * 4] = vv;
        }
        const float* Wb = W + ((size_t)kt * 64 + kb * 32) * CC;
        for (int i = t; i < 32 * CC; i += 256) ((float*)Bs)[i] = Wb[i];
        __syncthreads();
        #pragma unroll 4
        for (int k = 0; k < 32; ++k) {
            float a0 = As[tr * 4 + 0][k], a1 = As[tr * 4 + 1][k];
            float a2 = As[tr * 4 + 2][k], a3 = As[tr * 4 + 3][k];
            #pragma unroll
            for (int c = 0; c < 5; ++c) {
                float b = Bs[k][tc * 5 + c];
                acc[0][c] = fmaf(a0, b, acc[0][c]);
                acc[1][c] = fmaf(a1, b, acc[1][c]);
                acc[2][c] = fmaf(a2, b, acc[2][c]);
                acc[3][c] = fmaf(a3, b, acc[3][c]);
            }
        }
    }
    #pragma unroll
    for (int r = 0; r < 4; ++r) {
        int n = m0 + tr * 4 + r;
        if (n < NN) {
            float* orow = Y2f + (size_t)n * 256 + kt * 64;
            #pragma unroll
            for (int c = 0; c < 5; ++c) orow[tc * 5 + c] = acc[r][c];
            if (tc < 6) {
                #pragma unroll
                for (int c = 0; c < 4; ++c) orow[40 + tc * 4 + c] = 0.f;
            }
            if (kt == 3) {
                unsigned short* brow = y3b2 + (size_t)n * 64;
                #pragma unroll
                for (int c = 0; c < 5; ++c) brow[tc * 5 + c] = f2bf(acc[r][c]);
                if (tc < 6) {
                    #pragma unroll
                    for (int c = 0; c < 4; ++c) brow[40 + tc * 4 + c] = 0;
                }
            }
        }
    }
}

// ---------- launcher ----------
extern "C" void kernel_launch(void* const* d_in, const int* in_sizes, int n_in,
                              void* d_out, int out_size, void* d_ws, size_t ws_size,
                              hipStream_t stream) {
    const float* x    = (const float*)d_in[0];
    const int*   eidx = (const int*)d_in[1];
    const float* ew   = (const float*)d_in[2];
    const float* W1   = (const float*)d_in[3];
    const float* b1   = (const float*)d_in[4];
    const float* W2   = (const float*)d_in[5];
    const float* b2   = (const float*)d_in[6];
    float* out = (float*)d_out;

    const int* src = eidx;
    const int* dst = eidx + EE;

    // workspace carve-up
    float* p = (float*)d_ws;
    int2* csr = (int2*)p;             p += (size_t)2 * EE;        // 12.8 MB
    float* dis  = p;                  p += ((NN + 63) / 64) * 64;
    float* diag = p;                  p += ((NN + 63) / 64) * 64;
    float* Yf   = p;                  p += (size_t)NN * 256;      // 51.2 MB
    unsigned short* y3b = (unsigned short*)p;  p += (size_t)NN * 32;  // bf16 [N,64]
    unsigned short* u   = (unsigned short*)p;  p += (size_t)NN * 32;
    unsigned short* v   = (unsigned short*)p;  p += (size_t)NN * 32;
    float* h    = p;                  p += (size_t)NN * 64;       // 12.8 MB
    int* cnt       = (int*)p;
    int* row_start = cnt + NN;            // NN+1
    int* bsum      = row_start + NN + 1;
    int* boff      = bsum + NB;

    // setup partials alias Yf (dead before gemm1 writes Yf; stream-ordered)
    float* pdeg            = Yf;                                   // 64*NN floats
    unsigned short* pcnt64 = (unsigned short*)(Yf + (size_t)64 * NN);  // 64*NN ushorts
    int* pcnt16            = (int*)(Yf + (size_t)96 * NN);         // 16*NN ints
    float* Y2f = Yf;
    unsigned short* y3b2 = y3b;
    unsigned short* u2 = u;
    unsigned short* v2 = v;

    const int B = 256;
    hist_kernel<<<NCH * NSL, 1024, 0, stream>>>(src, dst, ew, pdeg, pcnt64);
    reduce_kernel<<<(NN + B - 1) / B, B, 0, stream>>>(pdeg, pcnt64, pcnt16, cnt, dis, diag);
    scanA_kernel<<<NB, 256, 0, stream>>>(cnt, bsum);
    scanB_kernel<<<1, 64, 0, stream>>>(bsum, boff, row_start);
    scanC_kernel<<<NB, 256, 0, stream>>>(cnt, boff, row_start);
    fill_kernel<<<NCHF * NSLF, 1024, 0, stream>>>(src, dst, ew, dis, row_start, pcnt16, csr);

    int pgrid = NN / 4;

    // ---- layer 1: project first, then 3 props in 64-dim ----
    gemm1_kernel<<<dim3((NN + 63) / 64, 4), 256, 0, stream>>>(x, W1, Yf, y3b);
    prop2_kernel<64, unsigned short><<<pgrid, 256, 0, stream>>>(
        y3b, 64, 4.f, Yf + 128, 2.f, nullptr, 0.f, 256,
        nullptr, 0, 64, 64, diag, row_start, csr, u);          // u = 4*L(y3) + 2*y2
    prop2_kernel<64, unsigned short><<<pgrid, 256, 0, stream>>>(
        u, 64, 1.f, Yf + 64, 1.f, Yf + 192, -3.f, 256,
        nullptr, 0, 64, 64, diag, row_start, csr, v);          // v = L(u) + y1 - 3*y3
    prop2_kernel<64, float><<<pgrid, 256, 0, stream>>>(
        v, 64, 1.f, Yf, 1.f, Yf + 128, -1.f, 256,
        b1, 1, 64, 64, diag, row_start, csr, h);               // h = relu(L(v)+y0-y2+b1)

    // ---- layer 2: project, then 3 props in 40(48)-dim ----
    gemm2_kernel<<<dim3((NN + 127) / 128, 4), 256, 0, stream>>>(h, W2, Y2f, y3b2);
    prop2_kernel<48, unsigned short><<<pgrid, 256, 0, stream>>>(
        y3b2, 64, 4.f, Y2f + 128, 2.f, nullptr, 0.f, 256,
        nullptr, 0, 48, 64, diag, row_start, csr, u2);
    prop2_kernel<48, unsigned short><<<pgrid, 256, 0, stream>>>(
        u2, 64, 1.f, Y2f + 64, 1.f, Y2f + 192, -3.f, 256,
        nullptr, 0, 48, 64, diag, row_start, csr, v2);
    prop2_kernel<48, float><<<pgrid, 256, 0, stream>>>(
        v2, 64, 1.f, Y2f, 1.f, Y2f + 128, -1.f, 256,
        b2, 0, 40, 40, diag, row_start, csr, out);
}